// Round 8
// baseline (289.359 us; speedup 1.0000x reference)
//
#include <hip/hip_runtime.h>
#include <hip/hip_bf16.h>

typedef __bf16 bf16;
typedef bf16 bf16x8 __attribute__((ext_vector_type(8)));
typedef bf16 bf16x4 __attribute__((ext_vector_type(4)));
typedef float f32x4 __attribute__((ext_vector_type(4)));

#define AS1 __attribute__((address_space(1)))
#define AS3 __attribute__((address_space(3)))

__device__ __forceinline__ void gload_lds16(const void* g, void* l) {
    __builtin_amdgcn_global_load_lds((const AS1 void*)g, (AS3 void*)l, 16, 0, 0);
}

__device__ __forceinline__ float tanh_fast(float x) {
    float xx = fminf(fmaxf(x, -15.0f), 15.0f);
    float e = __expf(2.0f * xx);
    return (e - 1.0f) / (e + 1.0f);
}

// ---------------------------------------------------------------------------
// Kernel 1: convert e1,e2 -> bf16 X=[e1|e2] (row-major [8192][4096]) and
// compute zs[m][c] = (1/2048) * dot(e1[r]*e2[r], W[c])  with r = 2048*m + c.
// ---------------------------------------------------------------------------
__global__ __launch_bounds__(256) void conv_x_zs(
    const float* __restrict__ e1, const float* __restrict__ e2,
    const float* __restrict__ W, bf16* __restrict__ Xb, float* __restrict__ zs)
{
    const int r = blockIdx.x;           // 0..8191
    const int t = threadIdx.x;          // 0..255, 8 elems each
    const int c = r & 2047, m = r >> 11;
    const size_t rb = (size_t)r * 2048;

    const float4* p1 = (const float4*)(e1 + rb) + t * 2;
    const float4* p2 = (const float4*)(e2 + rb) + t * 2;
    const float4* pw = (const float4*)(W + (size_t)c * 2048) + t * 2;
    float4 a0 = p1[0], a1 = p1[1];
    float4 b0 = p2[0], b1 = p2[1];
    float4 w0 = pw[0], w1 = pw[1];

    float dot = a0.x*b0.x*w0.x + a0.y*b0.y*w0.y + a0.z*b0.z*w0.z + a0.w*b0.w*w0.w
              + a1.x*b1.x*w1.x + a1.y*b1.y*w1.y + a1.z*b1.z*w1.z + a1.w*b1.w*w1.w;

    bf16x8 xa, xb;
    xa[0]=(bf16)a0.x; xa[1]=(bf16)a0.y; xa[2]=(bf16)a0.z; xa[3]=(bf16)a0.w;
    xa[4]=(bf16)a1.x; xa[5]=(bf16)a1.y; xa[6]=(bf16)a1.z; xa[7]=(bf16)a1.w;
    xb[0]=(bf16)b0.x; xb[1]=(bf16)b0.y; xb[2]=(bf16)b0.z; xb[3]=(bf16)b0.w;
    xb[4]=(bf16)b1.x; xb[5]=(bf16)b1.y; xb[6]=(bf16)b1.z; xb[7]=(bf16)b1.w;

    *(bf16x8*)(Xb + (size_t)r * 4096 + t * 8)        = xa;
    *(bf16x8*)(Xb + (size_t)r * 4096 + 2048 + t * 8) = xb;

    #pragma unroll
    for (int off = 32; off; off >>= 1) dot += __shfl_xor(dot, off);
    __shared__ float red[4];
    if ((t & 63) == 0) red[t >> 6] = dot;
    __syncthreads();
    if (t == 0) zs[m * 2048 + c] = (red[0] + red[1] + red[2] + red[3]) * (1.0f / 2048.0f);
}

// ---------------------------------------------------------------------------
// Kernel 2: V [4096][2048] f32  ->  Vt [2048][4096] bf16 (transposed, B^T)
// ---------------------------------------------------------------------------
__global__ __launch_bounds__(256) void conv_vt(const float* __restrict__ V,
                                               bf16* __restrict__ Vt)
{
    __shared__ float tile[64][65];
    const int k0 = (blockIdx.x >> 5) * 64;  // 64 k-tiles
    const int c0 = (blockIdx.x & 31) * 64;  // 32 c-tiles
    const int t = threadIdx.x;
    const int rr = t >> 4;
    const int cc = (t & 15) * 4;

    #pragma unroll
    for (int r4 = 0; r4 < 4; ++r4) {
        int row = r4 * 16 + rr;
        float4 v = *(const float4*)(V + (size_t)(k0 + row) * 2048 + c0 + cc);
        tile[row][cc + 0] = v.x; tile[row][cc + 1] = v.y;
        tile[row][cc + 2] = v.z; tile[row][cc + 3] = v.w;
    }
    __syncthreads();
    #pragma unroll
    for (int r4 = 0; r4 < 4; ++r4) {
        int crow = r4 * 16 + rr;   // c index within tile
        bf16x4 o;
        o[0] = (bf16)tile[cc + 0][crow];
        o[1] = (bf16)tile[cc + 1][crow];
        o[2] = (bf16)tile[cc + 2][crow];
        o[3] = (bf16)tile[cc + 3][crow];
        *(bf16x4*)(Vt + (size_t)(c0 + crow) * 4096 + k0 + cc) = o;
    }
}

// ---------------------------------------------------------------------------
// Kernel 3: 256x128-tile GEMM, BK=32, 4 waves (wave tile 128x64), LDS 48KB
// double-buffered -> 2 blocks/CU (grid 512). m97-style 1-barrier K-loop:
//   stage(t+1 -> other buf); ds_read buf c (12 b128); 32 MFMA; __syncthreads.
// Cross-block TLP (m114) hides the per-iteration drain; no manual phase
// machinery (r5/r7 lessons: 512-thr blocks cap regs at 256/wave, and extra
// barriers cost ~160cyc each at 2 lockstep waves/SIMD).
// amdgpu_waves_per_eu(2,2): pin allocator budget to 256 regs/wave so it
// doesn't spill chasing 4-wave occupancy that LDS precludes (r5 diagnosis).
// LDS rows are 64B (BK=32); swizzle key = (row&3)<<4 makes each 64-lane
// ds_read_b128 footprint a contiguous 1KB (conflict-free), staging source
// inverse-swizzled (rule #21), LDS dst linear.
// Co-resident blocks (bid, bid+256) share ntile -> same 1MB B-panel in XCD L2.
// ---------------------------------------------------------------------------
__global__ __attribute__((amdgpu_flat_work_group_size(256, 256),
                          amdgpu_waves_per_eu(2, 2)))
void gemm_ep(
    const bf16* __restrict__ Xb, const bf16* __restrict__ Vt,
    const float* __restrict__ zs, const float* __restrict__ bias,
    float* __restrict__ out)
{
    extern __shared__ char smem[];       // 2 x (A 16KB + B 8KB) = 49152 B
    const int tid  = threadIdx.x;        // 0..255
    const int lane = tid & 63;
    const int wid  = tid >> 6;           // 0..3
    const int wr = wid >> 1, wc = wid & 1;
    const int mtile = blockIdx.x >> 4;   // 32 row tiles (BM=256)
    const int ntile = blockIdx.x & 15;   // 16 col tiles (BN=128); bid%8 = XCD
    const int row0 = mtile * 256, col0 = ntile * 128;

    const int lr   = lane & 15;
    const int lkb  = (lane >> 4) * 16;   // k-slice byte offset (0..48)
    const int keyx = (lr & 3) << 4;      // read-side swizzle key (row&3)<<4

    // staging: thread t covers rows (t>>2)+r*64, 16B slot t&3 (64B rows)
    const int srow  = tid >> 2;          // 0..63
    const int scb   = ((tid & 3) * 16) ^ ((srow & 3) << 4);
    const bf16* Asrc = Xb + (size_t)(row0 + srow) * 4096 + (scb >> 1);
    const bf16* Bsrc = Vt + (size_t)(col0 + srow) * 4096 + (scb >> 1);

    f32x4 acc[8][4] = {};                // 128 regs (AGPR side)
    bf16x8 aA[8], bB[4];                 // 48 input regs

    auto stage = [&](int c, int kt) {
        char* Al = smem + c * 24576 + tid * 16;
        char* Bl = smem + c * 24576 + 16384 + tid * 16;
        const bf16* Ag = Asrc + kt * 32;
        const bf16* Bg = Bsrc + kt * 32;
        #pragma unroll
        for (int r = 0; r < 4; ++r)
            gload_lds16(Ag + (size_t)(r * 64) * 4096, Al + r * 4096);
        #pragma unroll
        for (int r = 0; r < 2; ++r)
            gload_lds16(Bg + (size_t)(r * 64) * 4096, Bl + r * 4096);
    };
    auto rdAB = [&](int c) {
        const char* Ab = smem + c * 24576;
        const char* Bb = Ab + 16384;
        #pragma unroll
        for (int i = 0; i < 8; ++i) {
            const int R = wr * 128 + i * 16 + lr;
            aA[i] = *(const bf16x8*)(Ab + R * 64 + (lkb ^ keyx));
        }
        #pragma unroll
        for (int j = 0; j < 4; ++j) {
            const int R = wc * 64 + j * 16 + lr;
            bB[j] = *(const bf16x8*)(Bb + R * 64 + (lkb ^ keyx));
        }
    };
    auto mm = [&]() {
        #pragma unroll
        for (int i = 0; i < 8; ++i)
            #pragma unroll
            for (int j = 0; j < 4; ++j)
                acc[i][j] = __builtin_amdgcn_mfma_f32_16x16x32_bf16(
                    aA[i], bB[j], acc[i][j], 0, 0, 0);
    };

    // prologue
    stage(0, 0);
    __syncthreads();

    // 128 K-tiles of 32; one __syncthreads per tile (drains vm+lgkm: the
    // prefetch of t+1 must land before t+1's reads, and all reads of the
    // buffer being overwritten at t+1 drained here — both all-waves).
    #pragma unroll 2
    for (int t = 0; t < 127; ++t) {
        const int c = t & 1;
        stage(c ^ 1, t + 1);     // issue early; lands under reads+MFMA
        rdAB(c);
        mm();
        __syncthreads();
    }
    rdAB(1);                     // t=127, buf 1, nothing in flight
    mm();

    // epilogue: out = tanh(acc + zs[p%4][c] + bias[c])
    // C/D layout (m89): col = lane&15, row = (lane>>4)*4 + q; p%4 == q here
    // (row0, wr*128, i*16, lq*4 all multiples of 4).
    const int lq = lane >> 4;
    #pragma unroll
    for (int j = 0; j < 4; ++j) {
        const int ccol = col0 + wc * 64 + j * 16 + lr;
        const float bb = bias[ccol];
        float zrow[4];
        #pragma unroll
        for (int q = 0; q < 4; ++q) zrow[q] = zs[q * 2048 + ccol] + bb;
        #pragma unroll
        for (int i = 0; i < 8; ++i) {
            const int prow = row0 + wr * 128 + i * 16 + lq * 4;
            #pragma unroll
            for (int q = 0; q < 4; ++q)
                out[(size_t)(prow + q) * 2048 + ccol] =
                    tanh_fast(acc[i][j][q] + zrow[q]);
        }
    }
}

// ---------------------------------------------------------------------------
extern "C" void kernel_launch(void* const* d_in, const int* in_sizes, int n_in,
                              void* d_out, int out_size, void* d_ws, size_t ws_size,
                              hipStream_t stream) {
    const float* e1 = (const float*)d_in[0];   // (8192, 2048)
    const float* e2 = (const float*)d_in[1];   // (8192, 2048)
    const float* W  = (const float*)d_in[2];   // (2048, 2048)
    const float* V  = (const float*)d_in[3];   // (4096, 2048)
    const float* b  = (const float*)d_in[4];   // (2048,)
    float* out = (float*)d_out;                // (8192, 2048) f32

    char* ws = (char*)d_ws;
    bf16*  Xb = (bf16*)ws;                                  // 64 MiB
    bf16*  Vt = (bf16*)(ws + (size_t)64 * 1024 * 1024);     // 16 MiB
    float* zs = (float*)(ws + (size_t)80 * 1024 * 1024);    // 32 KiB

    conv_x_zs<<<8192, 256, 0, stream>>>(e1, e2, W, Xb, zs);
    conv_vt<<<2048, 256, 0, stream>>>(V, Vt);

    hipFuncSetAttribute((const void*)gemm_ep,
                        hipFuncAttributeMaxDynamicSharedMemorySize, 49152);
    gemm_ep<<<512, 256, 49152, stream>>>(Xb, Vt, zs, b, out);
}

// Round 9
// 196.457 us; speedup vs baseline: 1.4729x; 1.4729x over previous
//
#include <hip/hip_runtime.h>
#include <hip/hip_bf16.h>

typedef __bf16 bf16;
typedef bf16 bf16x8 __attribute__((ext_vector_type(8)));
typedef bf16 bf16x4 __attribute__((ext_vector_type(4)));
typedef float f32x4 __attribute__((ext_vector_type(4)));

#define AS1 __attribute__((address_space(1)))
#define AS3 __attribute__((address_space(3)))

__device__ __forceinline__ void gload_lds16(const void* g, void* l) {
    __builtin_amdgcn_global_load_lds((const AS1 void*)g, (AS3 void*)l, 16, 0, 0);
}

__device__ __forceinline__ float tanh_fast(float x) {
    float xx = fminf(fmaxf(x, -15.0f), 15.0f);
    float e = __expf(2.0f * xx);
    return (e - 1.0f) / (e + 1.0f);
}

// ---------------------------------------------------------------------------
// Kernel 1: convert e1,e2 -> bf16 X=[e1|e2] (row-major [8192][4096]) and
// compute zs[m][c] = (1/2048) * dot(e1[r]*e2[r], W[c])  with r = 2048*m + c.
// ---------------------------------------------------------------------------
__global__ __launch_bounds__(256) void conv_x_zs(
    const float* __restrict__ e1, const float* __restrict__ e2,
    const float* __restrict__ W, bf16* __restrict__ Xb, float* __restrict__ zs)
{
    const int r = blockIdx.x;           // 0..8191
    const int t = threadIdx.x;          // 0..255, 8 elems each
    const int c = r & 2047, m = r >> 11;
    const size_t rb = (size_t)r * 2048;

    const float4* p1 = (const float4*)(e1 + rb) + t * 2;
    const float4* p2 = (const float4*)(e2 + rb) + t * 2;
    const float4* pw = (const float4*)(W + (size_t)c * 2048) + t * 2;
    float4 a0 = p1[0], a1 = p1[1];
    float4 b0 = p2[0], b1 = p2[1];
    float4 w0 = pw[0], w1 = pw[1];

    float dot = a0.x*b0.x*w0.x + a0.y*b0.y*w0.y + a0.z*b0.z*w0.z + a0.w*b0.w*w0.w
              + a1.x*b1.x*w1.x + a1.y*b1.y*w1.y + a1.z*b1.z*w1.z + a1.w*b1.w*w1.w;

    bf16x8 xa, xb;
    xa[0]=(bf16)a0.x; xa[1]=(bf16)a0.y; xa[2]=(bf16)a0.z; xa[3]=(bf16)a0.w;
    xa[4]=(bf16)a1.x; xa[5]=(bf16)a1.y; xa[6]=(bf16)a1.z; xa[7]=(bf16)a1.w;
    xb[0]=(bf16)b0.x; xb[1]=(bf16)b0.y; xb[2]=(bf16)b0.z; xb[3]=(bf16)b0.w;
    xb[4]=(bf16)b1.x; xb[5]=(bf16)b1.y; xb[6]=(bf16)b1.z; xb[7]=(bf16)b1.w;

    *(bf16x8*)(Xb + (size_t)r * 4096 + t * 8)        = xa;
    *(bf16x8*)(Xb + (size_t)r * 4096 + 2048 + t * 8) = xb;

    #pragma unroll
    for (int off = 32; off; off >>= 1) dot += __shfl_xor(dot, off);
    __shared__ float red[4];
    if ((t & 63) == 0) red[t >> 6] = dot;
    __syncthreads();
    if (t == 0) zs[m * 2048 + c] = (red[0] + red[1] + red[2] + red[3]) * (1.0f / 2048.0f);
}

// ---------------------------------------------------------------------------
// Kernel 2: V [4096][2048] f32  ->  Vt [2048][4096] bf16 (transposed, B^T)
// ---------------------------------------------------------------------------
__global__ __launch_bounds__(256) void conv_vt(const float* __restrict__ V,
                                               bf16* __restrict__ Vt)
{
    __shared__ float tile[64][65];
    const int k0 = (blockIdx.x >> 5) * 64;  // 64 k-tiles
    const int c0 = (blockIdx.x & 31) * 64;  // 32 c-tiles
    const int t = threadIdx.x;
    const int rr = t >> 4;
    const int cc = (t & 15) * 4;

    #pragma unroll
    for (int r4 = 0; r4 < 4; ++r4) {
        int row = r4 * 16 + rr;
        float4 v = *(const float4*)(V + (size_t)(k0 + row) * 2048 + c0 + cc);
        tile[row][cc + 0] = v.x; tile[row][cc + 1] = v.y;
        tile[row][cc + 2] = v.z; tile[row][cc + 3] = v.w;
    }
    __syncthreads();
    #pragma unroll
    for (int r4 = 0; r4 < 4; ++r4) {
        int crow = r4 * 16 + rr;   // c index within tile
        bf16x4 o;
        o[0] = (bf16)tile[cc + 0][crow];
        o[1] = (bf16)tile[cc + 1][crow];
        o[2] = (bf16)tile[cc + 2][crow];
        o[3] = (bf16)tile[cc + 3][crow];
        *(bf16x4*)(Vt + (size_t)(c0 + crow) * 4096 + k0 + cc) = o;
    }
}

// ---------------------------------------------------------------------------
// Kernel 3: 256x128-tile GEMM, BK=32, 4 waves (wave tile 128x64), TRIPLE-
// buffered LDS (3 x 24KB = 72KB) -> 2 blocks/CU (grid 512, cross-block TLP
// hides barrier drains, m114). One raw s_barrier per K-tile with COUNTED
// vmcnt(6) (r4's proven discipline; r8's vmcnt(0)-per-barrier exposed L3
// latency). Staging runs 2 tiles ahead:
//   iter t: stage(t+2 -> buf[(t+2)%3]); rdAB(buf[t%3]); mm; vmcnt(6); barrier
// WAR safety: buf[(t+2)%3] was read at iter t-1; every wave's reads drained
// (MFMA lgkm data-deps) before t-1's end barrier, and the stage is issued
// after it. RAW: vmcnt(6) at t's end leaves exactly t+2's 6 loads in flight,
// so tile t+1 has landed before any wave passes the barrier into iter t+1.
// Swizzle (fixed from r8): 64B rows -> key = ((row>>1)&3)<<4; each 16-lane
// ds_read_b128 group covers all 32 banks exactly 2-way (free, m136). r8's
// (row&3)<<4 gave 4-way (1.26e7 conflicts measured). Source inverse-swizzled
// (rule #21), LDS dest linear; key constant across 64-row staging steps.
// ---------------------------------------------------------------------------
__global__ __launch_bounds__(256, 2) void gemm_ep(
    const bf16* __restrict__ Xb, const bf16* __restrict__ Vt,
    const float* __restrict__ zs, const float* __restrict__ bias,
    float* __restrict__ out)
{
    extern __shared__ char smem[];       // 3 x (A 16KB + B 8KB) = 73728 B
    const int tid  = threadIdx.x;        // 0..255
    const int lane = tid & 63;
    const int wid  = tid >> 6;           // 0..3
    const int wr = wid >> 1, wc = wid & 1;
    const int mtile = blockIdx.x >> 4;   // 32 row tiles (BM=256)
    const int ntile = blockIdx.x & 15;   // 16 col tiles (BN=128)
    const int row0 = mtile * 256, col0 = ntile * 128;

    const int lr   = lane & 15;
    const int lkb  = (lane >> 4) * 16;       // k-slice byte (0..48), BK=32=64B
    const int keyx = ((lr >> 1) & 3) << 4;   // read-side swizzle key

    // staging: thread t covers row (t>>2), 16B slot (t&3); rows step by 64
    // per gload (64>>1 % 4 == 0 -> key constant across steps).
    const int srow  = tid >> 2;          // 0..63
    const int scb   = ((tid & 3) * 16) ^ (((srow >> 1) & 3) << 4);
    const bf16* Asrc = Xb + (size_t)(row0 + srow) * 4096 + (scb >> 1);
    const bf16* Bsrc = Vt + (size_t)(col0 + srow) * 4096 + (scb >> 1);

    f32x4 acc[8][4] = {};                // 128 acc regs
    bf16x8 aA[8], bB[4];                 // 48 input regs

    auto stage = [&](int b, int kt) {    // 6 gloads: A 16KB + B 8KB
        char* Al = smem + b * 24576 + tid * 16;
        char* Bl = smem + b * 24576 + 16384 + tid * 16;
        const bf16* Ag = Asrc + kt * 32;
        const bf16* Bg = Bsrc + kt * 32;
        #pragma unroll
        for (int r = 0; r < 4; ++r)
            gload_lds16(Ag + (size_t)(r * 64) * 4096, Al + r * 4096);
        #pragma unroll
        for (int r = 0; r < 2; ++r)
            gload_lds16(Bg + (size_t)(r * 64) * 4096, Bl + r * 4096);
    };
    auto rdAB = [&](int b) {             // 12 ds_read_b128
        const char* Ab = smem + b * 24576;
        const char* Bb = Ab + 16384;
        #pragma unroll
        for (int i = 0; i < 8; ++i) {
            const int R = wr * 128 + i * 16 + lr;
            aA[i] = *(const bf16x8*)(Ab + R * 64 + (lkb ^ keyx));
        }
        #pragma unroll
        for (int j = 0; j < 4; ++j) {
            const int R = wc * 64 + j * 16 + lr;
            bB[j] = *(const bf16x8*)(Bb + R * 64 + (lkb ^ keyx));
        }
    };
    auto mm = [&]() {                    // 32 MFMA
        __builtin_amdgcn_s_setprio(1);
        #pragma unroll
        for (int i = 0; i < 8; ++i)
            #pragma unroll
            for (int j = 0; j < 4; ++j)
                acc[i][j] = __builtin_amdgcn_mfma_f32_16x16x32_bf16(
                    aA[i], bB[j], acc[i][j], 0, 0, 0);
        __builtin_amdgcn_s_setprio(0);
    };

    // prologue: tiles 0,1 staged; vmcnt(6) -> tile 0 landed, tile 1 in flight
    stage(0, 0);
    stage(1, 1);
    asm volatile("s_waitcnt vmcnt(6)" ::: "memory");
    __builtin_amdgcn_s_barrier();

    // steady state: t = 0..125 (126 = 3*42 -> unroll 3 gives compile-time
    // buffer indices, rule #20)
    #pragma unroll 3
    for (int t = 0; t < 126; ++t) {
        const int rb = t % 3;            // read buffer
        const int sb = (t + 2) % 3;      // stage buffer (== (t-1)%3, WAR-safe)
        stage(sb, t + 2);
        rdAB(rb);
        mm();
        asm volatile("s_waitcnt vmcnt(6)" ::: "memory");   // tile t+1 landed
        __builtin_amdgcn_s_barrier();
    }
    // t = 126: no stage; drain tile 127's loads fully
    rdAB(0);
    mm();
    asm volatile("s_waitcnt vmcnt(0)" ::: "memory");
    __builtin_amdgcn_s_barrier();
    // t = 127: final tile, reads only
    rdAB(1);
    mm();

    // epilogue: out = tanh(acc + zs[p%4][c] + bias[c])
    // C/D layout (m89): col = lane&15, row = (lane>>4)*4 + q; p%4 == q here
    // (row0, wr*128, i*16, lq*4 all multiples of 4).
    const int lq = lane >> 4;
    #pragma unroll
    for (int j = 0; j < 4; ++j) {
        const int ccol = col0 + wc * 64 + j * 16 + lr;
        const float bb = bias[ccol];
        float zrow[4];
        #pragma unroll
        for (int q = 0; q < 4; ++q) zrow[q] = zs[q * 2048 + ccol] + bb;
        #pragma unroll
        for (int i = 0; i < 8; ++i) {
            const int prow = row0 + wr * 128 + i * 16 + lq * 4;
            #pragma unroll
            for (int q = 0; q < 4; ++q)
                out[(size_t)(prow + q) * 2048 + ccol] =
                    tanh_fast(acc[i][j][q] + zrow[q]);
        }
    }
}

// ---------------------------------------------------------------------------
extern "C" void kernel_launch(void* const* d_in, const int* in_sizes, int n_in,
                              void* d_out, int out_size, void* d_ws, size_t ws_size,
                              hipStream_t stream) {
    const float* e1 = (const float*)d_in[0];   // (8192, 2048)
    const float* e2 = (const float*)d_in[1];   // (8192, 2048)
    const float* W  = (const float*)d_in[2];   // (2048, 2048)
    const float* V  = (const float*)d_in[3];   // (4096, 2048)
    const float* b  = (const float*)d_in[4];   // (2048,)
    float* out = (float*)d_out;                // (8192, 2048) f32

    char* ws = (char*)d_ws;
    bf16*  Xb = (bf16*)ws;                                  // 64 MiB
    bf16*  Vt = (bf16*)(ws + (size_t)64 * 1024 * 1024);     // 16 MiB
    float* zs = (float*)(ws + (size_t)80 * 1024 * 1024);    // 32 KiB

    conv_x_zs<<<8192, 256, 0, stream>>>(e1, e2, W, Xb, zs);
    conv_vt<<<2048, 256, 0, stream>>>(V, Vt);

    hipFuncSetAttribute((const void*)gemm_ep,
                        hipFuncAttributeMaxDynamicSharedMemorySize, 73728);
    gemm_ep<<<512, 256, 73728, stream>>>(Xb, Vt, zs, b, out);
}